// Round 6
// baseline (350.688 us; speedup 1.0000x reference)
//
#include <hip/hip_runtime.h>

#define NZ 81          // 9x9 zones
#define OBS_DIM 48
#define MAX_ADJ 5
#define NTASK (NZ * MAX_ADJ)   // 405
#define TPAD 408               // padded task stride inside LDS rows
#define NEG_INF -1000000000.0f
#define BLOCK 512
#define ROWS 8                 // batch rows per block (acc[8] keeps VGPR < 64)
#define NPOS 13                // ceil(81*81 / 512) output positions per thread

__global__ __launch_bounds__(BLOCK, 8) void taxi_actor_kernel(
    const float* __restrict__ obs,   // [B, 48]
    const float* __restrict__ W,     // [81, 48, 5]
    const float* __restrict__ bias,  // [81, 5]
    const int*   __restrict__ idx,   // [81, 5]
    const float* __restrict__ mask,  // [81, 5]
    float* __restrict__ out)         // [B, 81, 81]
{
    __shared__ float s_obs[ROWS * OBS_DIM];   // 1.5 KB
    __shared__ float s_lp[ROWS][TPAD];        // 13 KB: logits, then probs in place
    __shared__ int   s_idx[NTASK];            // 1.6 KB (masked -> -1)

    const int tid = threadIdx.x;
    const size_t b0 = (size_t)blockIdx.x * ROWS;

    // Stage obs rows (coalesced) + adjacency.
    for (int i = tid; i < ROWS * OBS_DIM; i += BLOCK)
        s_obs[i] = obs[b0 * OBS_DIM + i];
    if (tid < NTASK)
        s_idx[tid] = (mask[tid] > 0.0f) ? idx[tid] : -1;
    __syncthreads();

    // Phase A: dot for all ROWS rows at once. Each W element is loaded once
    // and immediately consumed by ROWS FMAs -> no per-row W re-gather.
    if (tid < NTASK) {
        float acc[ROWS];
        #pragma unroll
        for (int r = 0; r < ROWS; ++r) acc[r] = 0.0f;
        const int n = tid / MAX_ADJ;
        const int k = tid - n * MAX_ADJ;
        const float* __restrict__ Wp = W + n * (OBS_DIM * MAX_ADJ) + k;
        #pragma unroll
        for (int d4 = 0; d4 < OBS_DIM; d4 += 4) {
            const float w0 = Wp[(d4 + 0) * MAX_ADJ];
            const float w1 = Wp[(d4 + 1) * MAX_ADJ];
            const float w2 = Wp[(d4 + 2) * MAX_ADJ];
            const float w3 = Wp[(d4 + 3) * MAX_ADJ];
            #pragma unroll
            for (int r = 0; r < ROWS; ++r) {
                const float4 o = *reinterpret_cast<const float4*>(&s_obs[r * OBS_DIM + d4]);
                acc[r] = fmaf(o.x, w0, acc[r]);
                acc[r] = fmaf(o.y, w1, acc[r]);
                acc[r] = fmaf(o.z, w2, acc[r]);
                acc[r] = fmaf(o.w, w3, acc[r]);
            }
        }
        const float bv = bias[tid];
        const bool valid = (s_idx[tid] >= 0);
        #pragma unroll
        for (int r = 0; r < ROWS; ++r)
            s_lp[r][tid] = valid ? (acc[r] + bv) : NEG_INF;
    }
    __syncthreads();

    // Softmax in place: ROWS*81 (row, zone) tasks over 512 threads.
    for (int j = tid; j < ROWS * NZ; j += BLOCK) {
        const int r = j / NZ;
        const int n = j - r * NZ;
        float l[MAX_ADJ];
        float m = NEG_INF;
        #pragma unroll
        for (int k = 0; k < MAX_ADJ; ++k) {
            l[k] = s_lp[r][n * MAX_ADJ + k];
            m = fmaxf(m, l[k]);
        }
        float ssum = 0.0f;
        #pragma unroll
        for (int k = 0; k < MAX_ADJ; ++k) {
            l[k] = __expf(l[k] - m);   // masked: exp(-1e9) -> 0
            ssum += l[k];
        }
        const float inv = 1.0f / ssum;
        #pragma unroll
        for (int k = 0; k < MAX_ADJ; ++k)
            s_lp[r][n * MAX_ADJ + k] = l[k] * inv;
    }
    __syncthreads();

    // Register inverse map, computed AFTER phase A so its 13 VGPRs don't
    // overlap the accumulators' live range (keeps peak pressure < 64).
    int tmap[NPOS];
    #pragma unroll
    for (int i = 0; i < NPOS; ++i) {
        tmap[i] = -1;
        const int p = tid + i * BLOCK;
        if (p < NZ * NZ) {
            const int n = p / NZ;
            const int z = p - n * NZ;
            #pragma unroll
            for (int k = 0; k < MAX_ADJ; ++k)
                if (s_idx[n * MAX_ADJ + k] == z) tmap[i] = n * MAX_ADJ + k;
        }
    }

    // Store burst: ROWS x 13 coalesced dword stores, no barriers, ~94% of
    // them immediate zeros (no LDS dependency on the zero path).
    for (int r = 0; r < ROWS; ++r) {
        float* __restrict__ ob = out + (b0 + r) * (size_t)(NZ * NZ);
        #pragma unroll
        for (int i = 0; i < NPOS; ++i) {
            const int p = tid + i * BLOCK;
            if (p < NZ * NZ)
                ob[p] = (tmap[i] >= 0) ? s_lp[r][tmap[i]] : 0.0f;
        }
    }
}

extern "C" void kernel_launch(void* const* d_in, const int* in_sizes, int n_in,
                              void* d_out, int out_size, void* d_ws, size_t ws_size,
                              hipStream_t stream) {
    const float* obs  = (const float*)d_in[0];
    const float* W    = (const float*)d_in[1];
    const float* bias = (const float*)d_in[2];
    const int*   idx  = (const int*)d_in[3];
    const float* mask = (const float*)d_in[4];
    float* out = (float*)d_out;

    const int B = in_sizes[0] / OBS_DIM;   // 32768, divisible by ROWS
    taxi_actor_kernel<<<B / ROWS, BLOCK, 0, stream>>>(obs, W, bias, idx, mask, out);
}

// Round 7
// 256.206 us; speedup vs baseline: 1.3688x; 1.3688x over previous
//
#include <hip/hip_runtime.h>

#define NZ 81          // 9x9 zones
#define OBS_DIM 48
#define MAX_ADJ 5
#define NTASK (NZ * MAX_ADJ)   // 405
#define TPAD 408               // padded task stride inside LDS rows
#define NEG_INF -1000000000.0f
#define BLOCK 512
#define ROWS 16                // batch rows per block
#define RCHUNK 8               // rows per accumulator chunk (keeps VGPR low)
#define NPOS 13                // ceil(81*81 / 512) output positions per thread

__global__ __launch_bounds__(BLOCK) void taxi_actor_kernel(
    const float* __restrict__ obs,   // [B, 48]
    const float* __restrict__ W,     // [81, 48, 5]
    const float* __restrict__ bias,  // [81, 5]
    const int*   __restrict__ idx,   // [81, 5]
    const float* __restrict__ mask,  // [81, 5]
    float* __restrict__ out)         // [B, 81, 81]
{
    __shared__ float s_obs[ROWS * OBS_DIM];   // 3 KB
    __shared__ float s_lp[ROWS][TPAD];        // 26.1 KB: logits, then probs in place
    __shared__ int   s_idx[NTASK];            // 1.6 KB (masked -> -1)

    const int tid = threadIdx.x;
    const size_t b0 = (size_t)blockIdx.x * ROWS;

    // Stage obs rows (coalesced) + adjacency.
    for (int i = tid; i < ROWS * OBS_DIM; i += BLOCK)
        s_obs[i] = obs[b0 * OBS_DIM + i];
    if (tid < NTASK)
        s_idx[tid] = (mask[tid] > 0.0f) ? idx[tid] : -1;
    __syncthreads();

    // Phase A: dot for 16 rows, processed as 2 chunks of 8 so only acc[8]
    // is live at once (peak VGPR ~30 here). W is read twice per block --
    // still 8x less W traffic than a per-row re-gather.
    if (tid < NTASK) {
        const int n = tid / MAX_ADJ;
        const int k = tid - n * MAX_ADJ;
        const float* __restrict__ Wp = W + n * (OBS_DIM * MAX_ADJ) + k;
        const float bv = bias[tid];
        const bool valid = (s_idx[tid] >= 0);

        for (int c = 0; c < ROWS; c += RCHUNK) {
            float acc[RCHUNK];
            #pragma unroll
            for (int r = 0; r < RCHUNK; ++r) acc[r] = 0.0f;
            #pragma unroll
            for (int d4 = 0; d4 < OBS_DIM; d4 += 4) {
                const float w0 = Wp[(d4 + 0) * MAX_ADJ];
                const float w1 = Wp[(d4 + 1) * MAX_ADJ];
                const float w2 = Wp[(d4 + 2) * MAX_ADJ];
                const float w3 = Wp[(d4 + 3) * MAX_ADJ];
                #pragma unroll
                for (int r = 0; r < RCHUNK; ++r) {
                    const float4 o = *reinterpret_cast<const float4*>(
                        &s_obs[(c + r) * OBS_DIM + d4]);
                    acc[r] = fmaf(o.x, w0, acc[r]);
                    acc[r] = fmaf(o.y, w1, acc[r]);
                    acc[r] = fmaf(o.z, w2, acc[r]);
                    acc[r] = fmaf(o.w, w3, acc[r]);
                }
            }
            #pragma unroll
            for (int r = 0; r < RCHUNK; ++r)
                s_lp[c + r][tid] = valid ? (acc[r] + bv) : NEG_INF;
        }
    }
    __syncthreads();

    // Softmax in place: 16*81 (row, zone) tasks over 512 threads.
    for (int j = tid; j < ROWS * NZ; j += BLOCK) {
        const int r = j / NZ;
        const int n = j - r * NZ;
        float l[MAX_ADJ];
        float m = NEG_INF;
        #pragma unroll
        for (int k = 0; k < MAX_ADJ; ++k) {
            l[k] = s_lp[r][n * MAX_ADJ + k];
            m = fmaxf(m, l[k]);
        }
        float ssum = 0.0f;
        #pragma unroll
        for (int k = 0; k < MAX_ADJ; ++k) {
            l[k] = __expf(l[k] - m);   // masked: exp(-1e9) -> 0
            ssum += l[k];
        }
        const float inv = 1.0f / ssum;
        #pragma unroll
        for (int k = 0; k < MAX_ADJ; ++k)
            s_lp[r][n * MAX_ADJ + k] = l[k] * inv;
    }
    __syncthreads();

    // Register inverse map, computed AFTER the accumulator phases so its 13
    // VGPRs never overlap acc[] live ranges.
    int tmap[NPOS];
    #pragma unroll
    for (int i = 0; i < NPOS; ++i) {
        tmap[i] = -1;
        const int p = tid + i * BLOCK;
        if (p < NZ * NZ) {
            const int n = p / NZ;
            const int z = p - n * NZ;
            #pragma unroll
            for (int k = 0; k < MAX_ADJ; ++k)
                if (s_idx[n * MAX_ADJ + k] == z) tmap[i] = n * MAX_ADJ + k;
        }
    }

    // Store burst: 16 rows x 13 coalesced dword stores, zero barriers, ~94%
    // immediate zeros (no LDS dependency on the zero path).
    for (int r = 0; r < ROWS; ++r) {
        float* __restrict__ ob = out + (b0 + r) * (size_t)(NZ * NZ);
        #pragma unroll
        for (int i = 0; i < NPOS; ++i) {
            const int p = tid + i * BLOCK;
            if (p < NZ * NZ)
                ob[p] = (tmap[i] >= 0) ? s_lp[r][tmap[i]] : 0.0f;
        }
    }
}

extern "C" void kernel_launch(void* const* d_in, const int* in_sizes, int n_in,
                              void* d_out, int out_size, void* d_ws, size_t ws_size,
                              hipStream_t stream) {
    const float* obs  = (const float*)d_in[0];
    const float* W    = (const float*)d_in[1];
    const float* bias = (const float*)d_in[2];
    const int*   idx  = (const int*)d_in[3];
    const float* mask = (const float*)d_in[4];
    float* out = (float*)d_out;

    const int B = in_sizes[0] / OBS_DIM;   // 32768, divisible by ROWS
    taxi_actor_kernel<<<B / ROWS, BLOCK, 0, stream>>>(obs, W, bias, idx, mask, out);
}